// Round 3
// baseline (2277.706 us; speedup 1.0000x reference)
//
#include <hip/hip_runtime.h>

#define NB 8        // batch
#define DIMC 128
#define KNBR 8

// ---------------- KNN: wave-per-query, wave-shared rejection threshold ----------------
// d' = |r|^2 - 2 q.r  (q^2 dropped: ranking-invariant per query).
// Self point has d' = -|q|^2 = global min, so EXCL masks it to +inf explicitly.
// thr = wave_min(bd[7]) is a safe reject bound: if d >= some lane's 8th-best, that
// lane already retains 8 elements <= d, so d can never enter the wave's final top-8.
#define KTILE 1024
template<bool EXCL>
__global__ __launch_bounds__(256) void knn_kernel(const float* __restrict__ ref,
                                                  const float* __restrict__ qry,
                                                  int Nr, int Nq, int* __restrict__ idx_out) {
  __shared__ float4 sref[KTILE];  // x,y,z,r2 : 16 KB
  int b = blockIdx.y;
  int wid = threadIdx.x >> 6, lane = threadIdx.x & 63;
  int qi = blockIdx.x * 4 + wid;
  const float* rb = ref + (size_t)b * 3 * Nr;
  const float* qb = qry + (size_t)b * 3 * Nq;
  float m2qx = -2.f * qb[qi], m2qy = -2.f * qb[Nq + qi], m2qz = -2.f * qb[2 * Nq + qi];
  float bd[KNBR]; int bi[KNBR];
#pragma unroll
  for (int t = 0; t < KNBR; t++) { bd[t] = 3.4e38f; bi[t] = 0; }
  float thr = 3.4e38f, myThr = 3.4e38f;
  for (int tile = 0; tile < Nr; tile += KTILE) {
    int cnt = min(KTILE, Nr - tile);   // always 1024 for our sizes
    __syncthreads();
    for (int j = threadIdx.x; j < cnt; j += 256) {
      float rx = rb[tile + j], ry = rb[Nr + tile + j], rz = rb[2 * Nr + tile + j];
      sref[j] = make_float4(rx, ry, rz, rx * rx + ry * ry + rz * rz);
    }
    __syncthreads();
    for (int base = 0; base < cnt; base += 512) {   // 8 candidates/lane per chunk
#pragma unroll
      for (int u = 0; u < 8; u++) {
        int j = base + u * 64 + lane;
        float4 r = sref[j];
        float d = fmaf(m2qx, r.x, fmaf(m2qy, r.y, fmaf(m2qz, r.z, r.w)));
        int gj = tile + j;
        if (EXCL) d = (gj == qi) ? 3.4e38f : d;
        if (d < myThr) {
          bd[KNBR - 1] = d; bi[KNBR - 1] = gj;
#pragma unroll
          for (int t = KNBR - 1; t > 0; t--)
            if (bd[t] < bd[t - 1]) {
              float td = bd[t]; bd[t] = bd[t - 1]; bd[t - 1] = td;
              int ti = bi[t]; bi[t] = bi[t - 1]; bi[t - 1] = ti;
            }
          myThr = fminf(thr, bd[KNBR - 1]);
        }
      }
      float t = bd[KNBR - 1];           // refresh wave bound
#pragma unroll
      for (int off = 32; off; off >>= 1) t = fminf(t, __shfl_xor(t, off));
      thr = t;
      myThr = fminf(thr, bd[KNBR - 1]);
    }
  }
  // 8-round wave merge: min over lanes of sorted heads, winner pops (static indices only)
  int myout = 0;
#pragma unroll
  for (int r = 0; r < KNBR; r++) {
    float d = bd[0]; int ix = bi[0];
#pragma unroll
    for (int off = 32; off; off >>= 1) {
      float d2 = __shfl_xor(d, off);
      int i2 = __shfl_xor(ix, off);
      if (d2 < d || (d2 == d && i2 < ix)) { d = d2; ix = i2; }
    }
    if (bd[0] == d && bi[0] == ix) {   // unique: each ref idx lives in exactly one lane
#pragma unroll
      for (int t = 0; t < KNBR - 1; t++) { bd[t] = bd[t + 1]; bi[t] = bi[t + 1]; }
      bd[KNBR - 1] = 3.4e38f;
    }
    if (lane == r) myout = ix;
  }
  if (lane < KNBR) idx_out[((size_t)b * Nq + qi) * KNBR + lane] = myout;
}

// ---------------- featurenet conv0: W0(128x3) applied to (gathered xyz - center) ----------------
__global__ void conv0_kernel(const float* __restrict__ xyz, const int* __restrict__ idx,
                             const float* __restrict__ W0, const float* __restrict__ b0,
                             float* __restrict__ out, int N) {
  size_t t = (size_t)blockIdx.x * blockDim.x + threadIdx.x;  // over NB*128*8*N
  int n = (int)(t % N); size_t r = t / N;
  int k = (int)(r % KNBR); r /= KNBR;
  int o = (int)(r % DIMC); int b = (int)(r / DIMC);
  const float* xb = xyz + (size_t)b * 3 * N;
  int j = idx[((size_t)b * N + n) * KNBR + k];
  float dx = xb[j] - xb[n];
  float dy = xb[N + j] - xb[N + n];
  float dz = xb[2 * N + j] - xb[2 * N + n];
  out[t] = W0[o * 3 + 0] * dx + W0[o * 3 + 1] * dy + W0[o * 3 + 2] * dz + b0[o];
}

// ---------------- fused BN stats+finalize: block per channel ----------------
__global__ __launch_bounds__(256) void statsfin_kernel(const float* __restrict__ x, int R,
                                                       const float* __restrict__ gamma,
                                                       const float* __restrict__ beta,
                                                       float2* __restrict__ ss) {
  int c = blockIdx.x;
  float s = 0.f, s2 = 0.f;
  for (int b = 0; b < NB; b++) {
    const float4* px = (const float4*)(x + ((size_t)(b * DIMC + c)) * R);
    for (int i = threadIdx.x; i < (R >> 2); i += 256) {
      float4 v = px[i];
      s += v.x + v.y + v.z + v.w;
      s2 += v.x * v.x + v.y * v.y + v.z * v.z + v.w * v.w;
    }
  }
#pragma unroll
  for (int off = 32; off; off >>= 1) { s += __shfl_down(s, off, 64); s2 += __shfl_down(s2, off, 64); }
  __shared__ float rs[4], rq[4];
  int w = threadIdx.x >> 6;
  if ((threadIdx.x & 63) == 0) { rs[w] = s; rq[w] = s2; }
  __syncthreads();
  if (threadIdx.x == 0) {
    float cntInv = 1.f / (NB * (float)R);
    float sum = rs[0] + rs[1] + rs[2] + rs[3];
    float sq = rq[0] + rq[1] + rq[2] + rq[3];
    float mean = sum * cntInv;
    float var = sq * cntInv - mean * mean;
    float sc = gamma[c] * rsqrtf(var + 1e-5f);
    ss[c] = make_float2(sc, beta[c] - mean * sc);
  }
}

// ---------------- fused GEMM: Y = alpha*(W @ f(X)) + bias [+ Y]  ----------------
// f(X) = relu(X*scale+shift) if ss != null else X.  W: 128x128 row-major [o][c].
// X/Y layout: [b][c][R] with per-batch channel stride R.
__global__ __launch_bounds__(256) void gemm_kernel(
    const float* __restrict__ X, const float2* __restrict__ ss,
    const float* __restrict__ W, const float* __restrict__ bias,
    float* __restrict__ Y, int R, float alpha, int addShortcut) {
  __shared__ float Wl[DIMC][64];
  __shared__ float Xl[64][68];
  int b = blockIdx.y;
  int r0 = blockIdx.x * 64;
  int cg = threadIdx.x & 15, rg = threadIdx.x >> 4;
  float acc[8][4] = {};
  const float* Xb = X + (size_t)b * DIMC * R;
  for (int kc = 0; kc < DIMC; kc += 64) {
    __syncthreads();
    for (int i = threadIdx.x; i < 2048; i += 256) {          // W chunk 128x64
      int o = i >> 4, c4 = (i & 15) << 2;
      *(float4*)&Wl[o][c4] = *(const float4*)&W[o * DIMC + kc + c4];
    }
    for (int i = threadIdx.x; i < 1024; i += 256) {          // X chunk 64x64
      int c = i >> 4, c4 = (i & 15) << 2;
      float4 v = *(const float4*)&Xb[(size_t)(kc + c) * R + r0 + c4];
      if (ss) {
        float2 t = ss[kc + c];
        v.x = fmaxf(v.x * t.x + t.y, 0.f); v.y = fmaxf(v.y * t.x + t.y, 0.f);
        v.z = fmaxf(v.z * t.x + t.y, 0.f); v.w = fmaxf(v.w * t.x + t.y, 0.f);
      }
      *(float4*)&Xl[c][c4] = v;
    }
    __syncthreads();
#pragma unroll
    for (int c0 = 0; c0 < 64; c0 += 4) {
      float4 xv0 = *(float4*)&Xl[c0 + 0][cg * 4];
      float4 xv1 = *(float4*)&Xl[c0 + 1][cg * 4];
      float4 xv2 = *(float4*)&Xl[c0 + 2][cg * 4];
      float4 xv3 = *(float4*)&Xl[c0 + 3][cg * 4];
#pragma unroll
      for (int r = 0; r < 8; r++) {
        float4 wv = *(float4*)&Wl[rg * 8 + r][c0];
        acc[r][0] += wv.x * xv0.x; acc[r][1] += wv.x * xv0.y; acc[r][2] += wv.x * xv0.z; acc[r][3] += wv.x * xv0.w;
        acc[r][0] += wv.y * xv1.x; acc[r][1] += wv.y * xv1.y; acc[r][2] += wv.y * xv1.z; acc[r][3] += wv.y * xv1.w;
        acc[r][0] += wv.z * xv2.x; acc[r][1] += wv.z * xv2.y; acc[r][2] += wv.z * xv2.z; acc[r][3] += wv.z * xv2.w;
        acc[r][0] += wv.w * xv3.x; acc[r][1] += wv.w * xv3.y; acc[r][2] += wv.w * xv3.z; acc[r][3] += wv.w * xv3.w;
      }
    }
  }
#pragma unroll
  for (int r = 0; r < 8; r++) {
    int o = rg * 8 + r;
    float bi = bias[o];
    float4 v;
    v.x = acc[r][0] * alpha + bi; v.y = acc[r][1] * alpha + bi;
    v.z = acc[r][2] * alpha + bi; v.w = acc[r][3] * alpha + bi;
    size_t off = ((size_t)b * DIMC + o) * R + r0 + cg * 4;
    if (addShortcut) {
      float4 sv = *(const float4*)&Y[off];
      v.x += sv.x; v.y += sv.y; v.z += sv.z; v.w += sv.w;
    }
    *(float4*)&Y[off] = v;
  }
}

// ---------------- featurenet epilogue: max over k of relu(bn(x)) ----------------
__global__ void maxk_kernel(const float* __restrict__ x, const float2* __restrict__ ss,
                            float* __restrict__ out, int N) {
  size_t t = (size_t)blockIdx.x * blockDim.x + threadIdx.x;  // over NB*128*N
  int n = (int)(t % N); size_t r = t / N; int o = (int)(r % DIMC); int b = (int)(r / DIMC);
  const float* p = x + ((size_t)(b * DIMC + o)) * KNBR * N + n;
  float2 s = ss[o];
  float m = 0.f;  // relu values are >= 0
#pragma unroll
  for (int k = 0; k < KNBR; k++) { float v = p[(size_t)k * N] * s.x + s.y; m = fmaxf(m, v); }
  out[t] = m;
}

// ---------------- res: p = relu(bn(points)); agg = p + sum_k p[nbr] ----------------
__global__ void agg_kernel(const float* __restrict__ pts, const float2* __restrict__ ss,
                           const int* __restrict__ idx, float* __restrict__ p,
                           float* __restrict__ agg, int N) {
  int n = blockIdx.x * 256 + threadIdx.x;
  int c0 = blockIdx.y * 4;
  int b = blockIdx.z;
  const int* ib = idx + ((size_t)b * N + n) * KNBR;
  int j[KNBR];
#pragma unroll
  for (int k = 0; k < KNBR; k++) j[k] = ib[k];
#pragma unroll
  for (int ci = 0; ci < 4; ci++) {
    int c = c0 + ci;
    const float* row = pts + ((size_t)b * DIMC + c) * N;
    float2 s = ss[c];
    float pv = fmaxf(row[n] * s.x + s.y, 0.f);
    float sum = pv;
#pragma unroll
    for (int k = 0; k < KNBR; k++) sum += fmaxf(row[j[k]] * s.x + s.y, 0.f);
    p[((size_t)b * DIMC + c) * N + n] = pv;
    agg[((size_t)b * DIMC + c) * N + n] = sum;
  }
}

// ---------------- unpool: new_xyz[b][d][u*N+n] = (Wc.p + Wn.s + bc + 8*bn)/9 + xyz ----------------
__global__ void newxyz_kernel(const float* __restrict__ p, const float* __restrict__ agg,
                              const float* __restrict__ Wc, const float* __restrict__ bc,
                              const float* __restrict__ Wn, const float* __restrict__ bn_,
                              const float* __restrict__ xyzc, float* __restrict__ out, int N) {
  int n = blockIdx.x * 256 + threadIdx.x;
  int b = blockIdx.y;
  float acc[6] = {};
  const float* pb = p + (size_t)b * DIMC * N + n;
  const float* ab = agg + (size_t)b * DIMC * N + n;
  for (int c = 0; c < DIMC; c++) {
    float pv = pb[(size_t)c * N];
    float sv = ab[(size_t)c * N] - pv;
#pragma unroll
    for (int jj = 0; jj < 6; jj++) acc[jj] += Wc[jj * DIMC + c] * pv + Wn[jj * DIMC + c] * sv;
  }
#pragma unroll
  for (int jj = 0; jj < 6; jj++) {
    float v = (acc[jj] + bc[jj] + 8.f * bn_[jj]) * (1.f / 9.f);
    int d = jj >> 1, u = jj & 1;
    out[((size_t)b * 3 + d) * (2 * N) + (size_t)u * N + n] = v + xyzc[((size_t)b * 3 + d) * N + n];
  }
}

// ---------------- interp: mean over k of gathered points ----------------
__global__ void gathermean_kernel(const float* __restrict__ pts, const int* __restrict__ idx,
                                  float* __restrict__ out, int Nin, int M) {
  int m = blockIdx.x * 256 + threadIdx.x;
  int c0 = blockIdx.y * 4, b = blockIdx.z;
  const int* ib = idx + ((size_t)b * M + m) * KNBR;
  int j[KNBR];
#pragma unroll
  for (int k = 0; k < KNBR; k++) j[k] = ib[k];
#pragma unroll
  for (int ci = 0; ci < 4; ci++) {
    int c = c0 + ci;
    const float* row = pts + ((size_t)b * DIMC + c) * Nin;
    float s = 0.f;
#pragma unroll
    for (int k = 0; k < KNBR; k++) s += row[j[k]];
    out[((size_t)b * DIMC + c) * M + m] = s * 0.125f;
  }
}

extern "C" void kernel_launch(void* const* d_in, const int* in_sizes, int n_in,
                              void* d_out, int out_size, void* d_ws, size_t ws_size,
                              hipStream_t stream) {
  const float* xyz    = (const float*)d_in[0];
  const float* fn_W0  = (const float*)d_in[1];
  const float* fn_b0  = (const float*)d_in[2];
  const float* fn_W   = (const float*)d_in[3];
  const float* fn_b   = (const float*)d_in[4];
  const float* fn_bng = (const float*)d_in[5];
  const float* fn_bnb = (const float*)d_in[6];
  const float* rb_bng = (const float*)d_in[7];
  const float* rb_bnb = (const float*)d_in[8];
  const float* rb_W   = (const float*)d_in[9];
  const float* rb_b   = (const float*)d_in[10];
  const float* rb_cW  = (const float*)d_in[11];
  const float* rb_cb  = (const float*)d_in[12];
  const float* rb_nW  = (const float*)d_in[13];
  const float* rb_nb  = (const float*)d_in[14];
  float* out = (float*)d_out;

  const int N1 = 2048, N2 = 4096;
  char* ws = (char*)d_ws;
  float* A    = (float*)ws;                         // 64 MiB: (8,128,8,2048) f32
  float* Bbuf = (float*)(ws + ((size_t)64 << 20));  // 64 MiB
  char* tail = ws + ((size_t)128 << 20);
  int* idx1 = (int*)tail;   tail += (size_t)NB * N1 * KNBR * 4;
  int* idxI = (int*)tail;   tail += (size_t)NB * N2 * KNBR * 4;
  int* idx2 = (int*)tail;   tail += (size_t)NB * N2 * KNBR * 4;
  float* nx1 = (float*)tail; tail += (size_t)NB * 3 * N2 * 4;
  float2* ssb  = (float2*)tail; tail += 128 * sizeof(float2);

  const size_t SZ1 = (size_t)NB * DIMC * N1;  // 2M floats
  const size_t SZ2 = (size_t)NB * DIMC * N2;  // 4M floats
  float* pts1 = Bbuf;             // after featurenet, Bbuf is free
  float* p1   = Bbuf + SZ1;
  float* agg1 = Bbuf + 2 * SZ1;
  float* pts2 = A;                // after featurenet+gathermean, A is free
  float* p2   = A + SZ2;
  float* agg2 = A + 2 * SZ2;

  // ---------- featurenet ----------
  knn_kernel<true><<<dim3(N1 / 4, NB), 256, 0, stream>>>(xyz, xyz, N1, N1, idx1);
  conv0_kernel<<<(NB * DIMC * KNBR * N1) / 256, 256, 0, stream>>>(xyz, idx1, fn_W0, fn_b0, A, N1);
  int Rf = KNBR * N1;  // 16384
  statsfin_kernel<<<128, 256, 0, stream>>>(A, Rf, fn_bng, fn_bnb, ssb);
  gemm_kernel<<<dim3(Rf / 64, NB), 256, 0, stream>>>(A, ssb, fn_W, fn_b, Bbuf, Rf, 1.f, 0);
  statsfin_kernel<<<128, 256, 0, stream>>>(Bbuf, Rf, fn_bng + 128, fn_bnb + 128, ssb);
  gemm_kernel<<<dim3(Rf / 64, NB), 256, 0, stream>>>(Bbuf, ssb, fn_W + 16384, fn_b + 128, A, Rf, 1.f, 0);
  statsfin_kernel<<<128, 256, 0, stream>>>(A, Rf, fn_bng + 256, fn_bnb + 256, ssb);
  maxk_kernel<<<(NB * DIMC * N1) / 256, 256, 0, stream>>>(A, ssb, pts1, N1);

  // ---------- stage 0 (N=2048, reuse idx1 since xyz identical) ----------
  for (int i = 0; i < 12; i++) {
    statsfin_kernel<<<128, 256, 0, stream>>>(pts1, N1, rb_bng + i * 128, rb_bnb + i * 128, ssb);
    agg_kernel<<<dim3(N1 / 256, 32, NB), 256, 0, stream>>>(pts1, ssb, idx1, p1, agg1, N1);
    gemm_kernel<<<dim3(N1 / 64, NB), 256, 0, stream>>>(agg1, nullptr, rb_W + (size_t)i * 16384,
                                                       rb_b + i * 128, pts1, N1, 1.f / 9.f, 1);
  }
  newxyz_kernel<<<dim3(N1 / 256, NB), 256, 0, stream>>>(p1, agg1, rb_cW, rb_cb, rb_nW, rb_nb,
                                                        xyz, nx1, N1);

  // ---------- interp to 4096 pts ----------
  knn_kernel<false><<<dim3(N2 / 4, NB), 256, 0, stream>>>(xyz, nx1, N1, N2, idxI);
  gathermean_kernel<<<dim3(N2 / 256, 32, NB), 256, 0, stream>>>(pts1, idxI, pts2, N1, N2);
  knn_kernel<true><<<dim3(N2 / 4, NB), 256, 0, stream>>>(nx1, nx1, N2, N2, idx2);

  // ---------- stage 1 (N=4096) ----------
  for (int i = 0; i < 12; i++) {
    statsfin_kernel<<<128, 256, 0, stream>>>(pts2, N2, rb_bng + (12 + i) * 128,
                                             rb_bnb + (12 + i) * 128, ssb);
    agg_kernel<<<dim3(N2 / 256, 32, NB), 256, 0, stream>>>(pts2, ssb, idx2, p2, agg2, N2);
    gemm_kernel<<<dim3(N2 / 64, NB), 256, 0, stream>>>(agg2, nullptr, rb_W + (size_t)(12 + i) * 16384,
                                                       rb_b + (12 + i) * 128, pts2, N2, 1.f / 9.f, 1);
  }
  newxyz_kernel<<<dim3(N2 / 256, NB), 256, 0, stream>>>(p2, agg2, rb_cW + 768, rb_cb + 6,
                                                        rb_nW + 768, rb_nb + 6, nx1, out, N2);
}

// Round 4
// 1991.679 us; speedup vs baseline: 1.1436x; 1.1436x over previous
//
#include <hip/hip_runtime.h>

#define NB 8
#define KNBR 8

// ---------------- KNN: wave-per-query, wave-uniform skip branch ----------------
#define KTILE 1024
template<bool EXCL>
__global__ __launch_bounds__(256) void knn_kernel(const float* __restrict__ ref,
                                                  const float* __restrict__ qry,
                                                  int Nr, int Nq, int* __restrict__ idx_out) {
  __shared__ float4 sref[KTILE];
  int b = blockIdx.y;
  int wid = threadIdx.x >> 6, lane = threadIdx.x & 63;
  int qi = blockIdx.x * 4 + wid;
  const float* rb = ref + (size_t)b * 3 * Nr;
  const float* qb = qry + (size_t)b * 3 * Nq;
  float m2qx = -2.f * qb[qi], m2qy = -2.f * qb[Nq + qi], m2qz = -2.f * qb[2 * Nq + qi];
  float bd[KNBR]; int bi[KNBR];
#pragma unroll
  for (int t = 0; t < KNBR; t++) { bd[t] = 3.4e38f; bi[t] = 0; }
  float thr = 3.4e38f, myThr = 3.4e38f;
  for (int tile = 0; tile < Nr; tile += KTILE) {
    int cnt = min(KTILE, Nr - tile);
    __syncthreads();
    for (int j = threadIdx.x; j < cnt; j += 256) {
      float rx = rb[tile + j], ry = rb[Nr + tile + j], rz = rb[2 * Nr + tile + j];
      sref[j] = make_float4(rx, ry, rz, rx * rx + ry * ry + rz * rz);
    }
    __syncthreads();
    for (int base = 0; base < cnt; base += 512) {
#pragma unroll
      for (int u = 0; u < 8; u++) {
        int j = base + u * 64 + lane;
        float4 r = sref[j];
        float d = fmaf(m2qx, r.x, fmaf(m2qy, r.y, fmaf(m2qz, r.z, r.w)));
        int gj = tile + j;
        if (EXCL) d = (gj == qi) ? 3.4e38f : d;
        bool ins = d < myThr;
        if (__any(ins)) {              // real uniform branch: skip insert when no lane needs it
          if (ins) {
            bd[KNBR - 1] = d; bi[KNBR - 1] = gj;
#pragma unroll
            for (int t = KNBR - 1; t > 0; t--)
              if (bd[t] < bd[t - 1]) {
                float td = bd[t]; bd[t] = bd[t - 1]; bd[t - 1] = td;
                int ti = bi[t]; bi[t] = bi[t - 1]; bi[t - 1] = ti;
              }
            myThr = fminf(thr, bd[KNBR - 1]);
          }
        }
      }
      float t = bd[KNBR - 1];
#pragma unroll
      for (int off = 32; off; off >>= 1) t = fminf(t, __shfl_xor(t, off));
      thr = t;
      myThr = fminf(thr, bd[KNBR - 1]);
    }
  }
  int myout = 0;
#pragma unroll
  for (int r = 0; r < KNBR; r++) {
    float d = bd[0]; int ix = bi[0];
#pragma unroll
    for (int off = 32; off; off >>= 1) {
      float d2 = __shfl_xor(d, off);
      int i2 = __shfl_xor(ix, off);
      if (d2 < d || (d2 == d && i2 < ix)) { d = d2; ix = i2; }
    }
    if (bd[0] == d && bi[0] == ix) {
#pragma unroll
      for (int t = 0; t < KNBR - 1; t++) { bd[t] = bd[t + 1]; bi[t] = bi[t + 1]; }
      bd[KNBR - 1] = 3.4e38f;
    }
    if (lane == r) myout = ix;
  }
  if (lane < KNBR) idx_out[((size_t)b * Nq + qi) * KNBR + lane] = myout;
}

// ---------------- conv0: row r=(pn*8+k), out[r][o] = W0[o]·(xyz[j]-xyz[n]) + b0 ----------------
__global__ void conv0_kernel(const float* __restrict__ xyz, const int* __restrict__ idx,
                             const float* __restrict__ W0, const float* __restrict__ b0,
                             float* __restrict__ outp, int N) {
  int r = blockIdx.x * 4 + (threadIdx.x >> 6);
  int lane = threadIdx.x & 63;
  int k = r & 7, pn = r >> 3;
  int n = pn & (N - 1), b = pn / N;
  const float* xb = xyz + (size_t)b * 3 * N;
  int j = idx[(size_t)pn * 8 + k];
  float dx = xb[j] - xb[n], dy = xb[N + j] - xb[N + n], dz = xb[2 * N + j] - xb[2 * N + n];
  int o = 2 * lane;
  float v0 = W0[o * 3] * dx + W0[o * 3 + 1] * dy + W0[o * 3 + 2] * dz + b0[o];
  float v1 = W0[o * 3 + 3] * dx + W0[o * 3 + 4] * dy + W0[o * 3 + 5] * dz + b0[o + 1];
  *(float2*)&outp[(size_t)r * 128 + o] = make_float2(v0, v1);
}

// ---------------- stats over rows -> per-block partials[blk][c]{s,s2} ----------------
__global__ __launch_bounds__(256) void statsrows_kernel(const float* __restrict__ x, int rpb,
                                                        float* __restrict__ partials) {
  int c4 = (threadIdx.x & 31) << 2, rg = threadIdx.x >> 5;
  float4 s = make_float4(0, 0, 0, 0), q = make_float4(0, 0, 0, 0);
  size_t r0 = (size_t)blockIdx.x * rpb;
  for (int r = rg; r < rpb; r += 8) {
    float4 v = *(const float4*)&x[(r0 + r) * 128 + c4];
    s.x += v.x; s.y += v.y; s.z += v.z; s.w += v.w;
    q.x += v.x * v.x; q.y += v.y * v.y; q.z += v.z * v.z; q.w += v.w * v.w;
  }
  __shared__ float rs[8][128], rq[8][128];
  *(float4*)&rs[rg][c4] = s;
  *(float4*)&rq[rg][c4] = q;
  __syncthreads();
  if (threadIdx.x < 128) {
    int c = threadIdx.x;
    float ss_ = 0, qq = 0;
#pragma unroll
    for (int g = 0; g < 8; g++) { ss_ += rs[g][c]; qq += rq[g][c]; }
    *(float2*)&partials[((size_t)blockIdx.x * 128 + c) * 2] = make_float2(ss_, qq);
  }
}

// ---------------- finalize: reduce partials -> scale/shift ----------------
__global__ void finalize_kernel(const float* __restrict__ partials, int nblk, float cntInv,
                                const float* __restrict__ gamma, const float* __restrict__ beta,
                                float2* __restrict__ ss) {
  int c = blockIdx.x;
  float s = 0, q = 0;
  for (int i = threadIdx.x; i < nblk; i += 64) {
    float2 v = *(const float2*)&partials[((size_t)i * 128 + c) * 2];
    s += v.x; q += v.y;
  }
#pragma unroll
  for (int off = 32; off; off >>= 1) { s += __shfl_xor(s, off); q += __shfl_xor(q, off); }
  if (threadIdx.x == 0) {
    float mean = s * cntInv;
    float var = q * cntInv - mean * mean;
    float sc = gamma[c] * rsqrtf(var + 1e-5f);
    ss[c] = make_float2(sc, beta[c] - mean * sc);
  }
}

// ---------------- fused: [gather+bn-relu+sum] -> GEMM -> bias/alpha/shortcut -> stats partials ----
// Xin/Y: [RT][128] point-major. W: [o][c] row-major. GATHER: agg = relu'd center + 8 relu'd nbrs.
template<bool GATHER>
__global__ __launch_bounds__(256) void gemmf_kernel(
    const float* __restrict__ Xin, const float2* __restrict__ ss,
    const int* __restrict__ idx, const float* __restrict__ W,
    const float* __restrict__ bias, float* __restrict__ Y,
    float* __restrict__ partials, float* __restrict__ pOut, float* __restrict__ aggOut,
    int N, float alpha, int addShortcut) {
  __shared__ float Xl[64 * 66];   // [c-chunk 64][n 64] stride 66
  __shared__ float Wl[128 * 64];  // [o][c-chunk 64]
  int tid = threadIdx.x;
  int lane = tid & 63, wid = tid >> 6;
  int cg = tid & 15, og = tid >> 4;
  int row0 = blockIdx.x * 64;
  float acc[8][4] = {};
  for (int kc = 0; kc < 128; kc += 64) {
    __syncthreads();
    for (int i = tid; i < 2048; i += 256) {
      int o = i >> 4, c4 = (i & 15) << 2;
      *(float4*)&Wl[o * 64 + c4] = *(const float4*)&W[o * 128 + kc + c4];
    }
    float2 sv = ss[kc + lane];
    for (int pass = 0; pass < 16; pass++) {
      int nloc = pass * 4 + wid;
      size_t rg = (size_t)(row0 + nloc);
      float v = Xin[rg * 128 + kc + lane];
      float s = fmaxf(v * sv.x + sv.y, 0.f);
      if (GATHER) {
        if (pOut) pOut[rg * 128 + kc + lane] = s;
        int bN = (row0 + nloc) & ~(N - 1);
        const int* ir = idx + rg * 8;
        int4 j0 = *(const int4*)ir;
        int4 j1 = *(const int4*)(ir + 4);
        float g0 = Xin[(size_t)(bN + j0.x) * 128 + kc + lane];
        float g1 = Xin[(size_t)(bN + j0.y) * 128 + kc + lane];
        float g2 = Xin[(size_t)(bN + j0.z) * 128 + kc + lane];
        float g3 = Xin[(size_t)(bN + j0.w) * 128 + kc + lane];
        float g4 = Xin[(size_t)(bN + j1.x) * 128 + kc + lane];
        float g5 = Xin[(size_t)(bN + j1.y) * 128 + kc + lane];
        float g6 = Xin[(size_t)(bN + j1.z) * 128 + kc + lane];
        float g7 = Xin[(size_t)(bN + j1.w) * 128 + kc + lane];
        s += fmaxf(g0 * sv.x + sv.y, 0.f) + fmaxf(g1 * sv.x + sv.y, 0.f) +
             fmaxf(g2 * sv.x + sv.y, 0.f) + fmaxf(g3 * sv.x + sv.y, 0.f) +
             fmaxf(g4 * sv.x + sv.y, 0.f) + fmaxf(g5 * sv.x + sv.y, 0.f) +
             fmaxf(g6 * sv.x + sv.y, 0.f) + fmaxf(g7 * sv.x + sv.y, 0.f);
        if (aggOut) aggOut[rg * 128 + kc + lane] = s;
      }
      Xl[lane * 66 + nloc] = s;
    }
    __syncthreads();
#pragma unroll
    for (int c0 = 0; c0 < 64; c0 += 4) {
      float2 xa[4], xb[4];
#pragma unroll
      for (int cj = 0; cj < 4; cj++) {
        xa[cj] = *(const float2*)&Xl[(c0 + cj) * 66 + cg * 4];
        xb[cj] = *(const float2*)&Xl[(c0 + cj) * 66 + cg * 4 + 2];
      }
#pragma unroll
      for (int r = 0; r < 8; r++) {
        float4 wv = *(const float4*)&Wl[(og * 8 + r) * 64 + c0];
        acc[r][0] += wv.x * xa[0].x; acc[r][1] += wv.x * xa[0].y; acc[r][2] += wv.x * xb[0].x; acc[r][3] += wv.x * xb[0].y;
        acc[r][0] += wv.y * xa[1].x; acc[r][1] += wv.y * xa[1].y; acc[r][2] += wv.y * xb[1].x; acc[r][3] += wv.y * xb[1].y;
        acc[r][0] += wv.z * xa[2].x; acc[r][1] += wv.z * xa[2].y; acc[r][2] += wv.z * xb[2].x; acc[r][3] += wv.z * xb[2].y;
        acc[r][0] += wv.w * xa[3].x; acc[r][1] += wv.w * xa[3].y; acc[r][2] += wv.w * xb[3].x; acc[r][3] += wv.w * xb[3].y;
      }
    }
  }
  float4 bA = *(const float4*)&bias[og * 8];
  float4 bB = *(const float4*)&bias[og * 8 + 4];
  float pS[8] = {}, pQ[8] = {};
  int colb = og * 8;
#pragma unroll
  for (int i = 0; i < 4; i++) {
    size_t row = (size_t)(row0 + cg * 4 + i);
    float4 vA, vB;
    vA.x = acc[0][i] * alpha + bA.x; vA.y = acc[1][i] * alpha + bA.y;
    vA.z = acc[2][i] * alpha + bA.z; vA.w = acc[3][i] * alpha + bA.w;
    vB.x = acc[4][i] * alpha + bB.x; vB.y = acc[5][i] * alpha + bB.y;
    vB.z = acc[6][i] * alpha + bB.z; vB.w = acc[7][i] * alpha + bB.w;
    if (addShortcut) {
      float4 sA = *(const float4*)&Xin[row * 128 + colb];
      float4 sB = *(const float4*)&Xin[row * 128 + colb + 4];
      vA.x += sA.x; vA.y += sA.y; vA.z += sA.z; vA.w += sA.w;
      vB.x += sB.x; vB.y += sB.y; vB.z += sB.z; vB.w += sB.w;
    }
    *(float4*)&Y[row * 128 + colb] = vA;
    *(float4*)&Y[row * 128 + colb + 4] = vB;
    pS[0] += vA.x; pQ[0] += vA.x * vA.x; pS[1] += vA.y; pQ[1] += vA.y * vA.y;
    pS[2] += vA.z; pQ[2] += vA.z * vA.z; pS[3] += vA.w; pQ[3] += vA.w * vA.w;
    pS[4] += vB.x; pQ[4] += vB.x * vB.x; pS[5] += vB.y; pQ[5] += vB.y * vB.y;
    pS[6] += vB.z; pQ[6] += vB.z * vB.z; pS[7] += vB.w; pQ[7] += vB.w * vB.w;
  }
#pragma unroll
  for (int off = 1; off < 16; off <<= 1) {
#pragma unroll
    for (int r = 0; r < 8; r++) { pS[r] += __shfl_xor(pS[r], off); pQ[r] += __shfl_xor(pQ[r], off); }
  }
  if (cg == 0) {
#pragma unroll
    for (int r = 0; r < 8; r++)
      *(float2*)&partials[((size_t)blockIdx.x * 128 + og * 8 + r) * 2] = make_float2(pS[r], pQ[r]);
  }
}

// ---------------- maxk: pts[pn][c] = max_k relu(bn(x[pn*8+k][c])) ----------------
__global__ void maxk_kernel(const float* __restrict__ x, const float2* __restrict__ ss,
                            float* __restrict__ outp) {
  int pr = blockIdx.x * 4 + (threadIdx.x >> 6);
  int lane = threadIdx.x & 63;
  float2 sA = ss[2 * lane], sB = ss[2 * lane + 1];
  const float* px = x + (size_t)pr * 8 * 128 + 2 * lane;
  float m0 = 0.f, m1 = 0.f;
#pragma unroll
  for (int k = 0; k < 8; k++) {
    float2 v = *(const float2*)(px + (size_t)k * 128);
    m0 = fmaxf(m0, v.x * sA.x + sA.y);
    m1 = fmaxf(m1, v.y * sB.x + sB.y);
  }
  *(float2*)&outp[(size_t)pr * 128 + 2 * lane] = make_float2(m0, m1);
}

// ---------------- gathermean: out[r][c] = mean_k pts[bNin + j_k][c] ----------------
__global__ void gathermean_kernel(const float* __restrict__ pts, const int* __restrict__ idx,
                                  float* __restrict__ outp, int Nin, int Nout) {
  int r = blockIdx.x * 4 + (threadIdx.x >> 6);
  int lane = threadIdx.x & 63;
  int bbase = (r / Nout) * Nin;
  const int4* ir = (const int4*)(idx + (size_t)r * 8);
  int4 j0 = ir[0], j1 = ir[1];
  float2 s = make_float2(0.f, 0.f);
  int js[8] = {j0.x, j0.y, j0.z, j0.w, j1.x, j1.y, j1.z, j1.w};
#pragma unroll
  for (int k = 0; k < 8; k++) {
    float2 v = *(const float2*)&pts[(size_t)(bbase + js[k]) * 128 + 2 * lane];
    s.x += v.x; s.y += v.y;
  }
  *(float2*)&outp[(size_t)r * 128 + 2 * lane] = make_float2(s.x * 0.125f, s.y * 0.125f);
}

// ---------------- newxyz: out[b][d][u*N+n] = (Wc·p + Wn·(agg-p) + bc + 8bn)/9 + xyz ----------------
__global__ __launch_bounds__(256) void newxyz_kernel(
    const float* __restrict__ p, const float* __restrict__ agg,
    const float* __restrict__ Wc, const float* __restrict__ bc,
    const float* __restrict__ Wn, const float* __restrict__ bn_,
    const float* __restrict__ xyzc, float* __restrict__ outp, int N) {
  __shared__ float wc[6][128], wn[6][128];
  for (int i = threadIdx.x; i < 768; i += 256) { wc[i >> 7][i & 127] = Wc[i]; wn[i >> 7][i & 127] = Wn[i]; }
  __syncthreads();
  int pr = blockIdx.x * 4 + (threadIdx.x >> 6);
  int lane = threadIdx.x & 63;
  int b = pr / N, n = pr % N;
  float2 pv = *(const float2*)&p[(size_t)pr * 128 + 2 * lane];
  float2 av = *(const float2*)&agg[(size_t)pr * 128 + 2 * lane];
  float2 gv = make_float2(av.x - pv.x, av.y - pv.y);
  float a[6];
#pragma unroll
  for (int j = 0; j < 6; j++)
    a[j] = wc[j][2 * lane] * pv.x + wc[j][2 * lane + 1] * pv.y +
           wn[j][2 * lane] * gv.x + wn[j][2 * lane + 1] * gv.y;
#pragma unroll
  for (int j = 0; j < 6; j++)
#pragma unroll
    for (int off = 32; off; off >>= 1) a[j] += __shfl_xor(a[j], off);
  if (lane == 0) {
#pragma unroll
    for (int j = 0; j < 6; j++) {
      int d = j >> 1, u = j & 1;
      float v = (a[j] + bc[j] + 8.f * bn_[j]) * (1.f / 9.f);
      outp[((size_t)b * 3 + d) * (2 * N) + (size_t)u * N + n] = v + xyzc[((size_t)b * 3 + d) * N + n];
    }
  }
}

extern "C" void kernel_launch(void* const* d_in, const int* in_sizes, int n_in,
                              void* d_out, int out_size, void* d_ws, size_t ws_size,
                              hipStream_t stream) {
  const float* xyz    = (const float*)d_in[0];
  const float* fn_W0  = (const float*)d_in[1];
  const float* fn_b0  = (const float*)d_in[2];
  const float* fn_W   = (const float*)d_in[3];
  const float* fn_b   = (const float*)d_in[4];
  const float* fn_bng = (const float*)d_in[5];
  const float* fn_bnb = (const float*)d_in[6];
  const float* rb_bng = (const float*)d_in[7];
  const float* rb_bnb = (const float*)d_in[8];
  const float* rb_W   = (const float*)d_in[9];
  const float* rb_b   = (const float*)d_in[10];
  const float* rb_cW  = (const float*)d_in[11];
  const float* rb_cb  = (const float*)d_in[12];
  const float* rb_nW  = (const float*)d_in[13];
  const float* rb_nb  = (const float*)d_in[14];
  float* out = (float*)d_out;

  const int N1 = 2048, N2 = 4096;
  const int RT0 = NB * N1 * 8;   // 131072 featurenet rows
  const int RT1 = NB * N1;       // 16384
  const int RT2 = NB * N2;       // 32768
  char* ws = (char*)d_ws;
  float* A = (float*)ws;                          // 64 MiB
  float* B = (float*)(ws + ((size_t)64 << 20));   // 64 MiB
  char* tail = ws + ((size_t)128 << 20);
  int* idx1 = (int*)tail;    tail += (size_t)RT1 * 8 * 4;
  int* idxI = (int*)tail;    tail += (size_t)RT2 * 8 * 4;
  int* idx2 = (int*)tail;    tail += (size_t)RT2 * 8 * 4;
  float* nx1 = (float*)tail; tail += (size_t)NB * 3 * N2 * 4;
  float* partials = (float*)tail; tail += (size_t)2048 * 128 * 2 * 4;
  float2* ssb = (float2*)tail; tail += 128 * sizeof(float2);

  float* X0 = A;                       // [131072][128] = 64 MiB
  float* X1 = B;                       // 64 MiB
  // after featurenet: B free for stage0 (pts1 ping-pong + p1/agg1), A free after maxk for stage1
  const size_t M8 = (size_t)(8 << 20) / 4;
  float* pts1a = B;            float* pts1b = B + M8;
  float* p1 = B + 2 * M8;      float* agg1 = B + 3 * M8;
  const size_t M16 = (size_t)(16 << 20) / 4;
  float* pts2a = A;            float* pts2b = A + M16;
  float* p2 = A + 2 * M16;     float* agg2 = A + 3 * M16;

  // ---------- featurenet ----------
  knn_kernel<true><<<dim3(N1 / 4, NB), 256, 0, stream>>>(xyz, xyz, N1, N1, idx1);
  conv0_kernel<<<RT0 / 4, 256, 0, stream>>>(xyz, idx1, fn_W0, fn_b0, X0, N1);
  statsrows_kernel<<<256, 256, 0, stream>>>(X0, RT0 / 256, partials);
  finalize_kernel<<<128, 64, 0, stream>>>(partials, 256, 1.f / (float)RT0, fn_bng, fn_bnb, ssb);
  gemmf_kernel<false><<<RT0 / 64, 256, 0, stream>>>(X0, ssb, nullptr, fn_W, fn_b, X1,
                                                    partials, nullptr, nullptr, 1, 1.f, 0);
  finalize_kernel<<<128, 64, 0, stream>>>(partials, RT0 / 64, 1.f / (float)RT0,
                                          fn_bng + 128, fn_bnb + 128, ssb);
  gemmf_kernel<false><<<RT0 / 64, 256, 0, stream>>>(X1, ssb, nullptr, fn_W + 16384, fn_b + 128, X0,
                                                    partials, nullptr, nullptr, 1, 1.f, 0);
  finalize_kernel<<<128, 64, 0, stream>>>(partials, RT0 / 64, 1.f / (float)RT0,
                                          fn_bng + 256, fn_bnb + 256, ssb);
  maxk_kernel<<<RT1 / 4, 256, 0, stream>>>(X0, ssb, pts1a);

  // ---------- stage 0 (N=2048) ----------
  statsrows_kernel<<<256, 256, 0, stream>>>(pts1a, RT1 / 256, partials);
  float* cur = pts1a;
  float* alt = pts1b;
  for (int i = 0; i < 12; i++) {
    finalize_kernel<<<128, 64, 0, stream>>>(partials, (i == 0) ? 256 : RT1 / 64,
                                            1.f / (float)RT1, rb_bng + i * 128, rb_bnb + i * 128, ssb);
    gemmf_kernel<true><<<RT1 / 64, 256, 0, stream>>>(cur, ssb, idx1, rb_W + (size_t)i * 16384,
                                                     rb_b + i * 128, alt, partials,
                                                     (i == 11) ? p1 : nullptr,
                                                     (i == 11) ? agg1 : nullptr,
                                                     N1, 1.f / 9.f, 1);
    float* t = cur; cur = alt; alt = t;
  }
  newxyz_kernel<<<RT1 / 4, 256, 0, stream>>>(p1, agg1, rb_cW, rb_cb, rb_nW, rb_nb, xyz, nx1, N1);

  // ---------- interp to 4096 ----------
  knn_kernel<false><<<dim3(N2 / 4, NB), 256, 0, stream>>>(xyz, nx1, N1, N2, idxI);
  gathermean_kernel<<<RT2 / 4, 256, 0, stream>>>(cur, idxI, pts2a, N1, N2);
  knn_kernel<true><<<dim3(N2 / 4, NB), 256, 0, stream>>>(nx1, nx1, N2, N2, idx2);

  // ---------- stage 1 (N=4096) ----------
  statsrows_kernel<<<256, 256, 0, stream>>>(pts2a, RT2 / 256, partials);
  cur = pts2a; alt = pts2b;
  for (int i = 0; i < 12; i++) {
    finalize_kernel<<<128, 64, 0, stream>>>(partials, (i == 0) ? 256 : RT2 / 64,
                                            1.f / (float)RT2, rb_bng + (12 + i) * 128,
                                            rb_bnb + (12 + i) * 128, ssb);
    gemmf_kernel<true><<<RT2 / 64, 256, 0, stream>>>(cur, ssb, idx2, rb_W + (size_t)(12 + i) * 16384,
                                                     rb_b + (12 + i) * 128, alt, partials,
                                                     (i == 11) ? p2 : nullptr,
                                                     (i == 11) ? agg2 : nullptr,
                                                     N2, 1.f / 9.f, 1);
    float* t = cur; cur = alt; alt = t;
  }
  newxyz_kernel<<<RT2 / 4, 256, 0, stream>>>(p2, agg2, rb_cW + 768, rb_cb + 6,
                                             rb_nW + 768, rb_nb + 6, nx1, out, N2);
}